// Round 6
// baseline (6908.582 us; speedup 1.0000x reference)
//
#include <hip/hip_runtime.h>
#include <hip/hip_cooperative_groups.h>
#include <stdint.h>

namespace cg = cooperative_groups;

#define NPED 256   // agents
#define DH   128   // hidden dim
#define NEMB 64    // embedding dim
#define NG   64    // grid cells (8x8)
#define TOBS 8
#define TPRED 12
#define NBLK 256   // == CU count; 257 exceeded the cooperative co-residency
                   // limit (49.4KB LDS -> 1 block/CU) and the launch silently
                   // failed with CooperativeLaunchTooLarge

// ---------- cross-XCD coherence fences (gfx950: per-XCD L2 NOT coherent) ----
__device__ __forceinline__ void fence_release_agent() {
  __builtin_amdgcn_fence(__ATOMIC_RELEASE, "agent");
}
__device__ __forceinline__ void fence_acquire_agent() {
  __builtin_amdgcn_fence(__ATOMIC_ACQUIRE, "agent");
}

// ---------- JAX-compatible Threefry2x32 ----------
__device__ __forceinline__ uint32_t rotl32(uint32_t v, int n) {
  return (v << n) | (v >> (32 - n));
}

__device__ __forceinline__ void threefry2x32(uint32_t k0, uint32_t k1,
                                             uint32_t x0, uint32_t x1,
                                             uint32_t& o0, uint32_t& o1) {
  uint32_t ks2 = k0 ^ k1 ^ 0x1BD11BDAu;
  x0 += k0; x1 += k1;
  x0 += x1; x1 = rotl32(x1, 13); x1 ^= x0;
  x0 += x1; x1 = rotl32(x1, 15); x1 ^= x0;
  x0 += x1; x1 = rotl32(x1, 26); x1 ^= x0;
  x0 += x1; x1 = rotl32(x1,  6); x1 ^= x0;
  x0 += k1; x1 += ks2 + 1u;
  x0 += x1; x1 = rotl32(x1, 17); x1 ^= x0;
  x0 += x1; x1 = rotl32(x1, 29); x1 ^= x0;
  x0 += x1; x1 = rotl32(x1, 16); x1 ^= x0;
  x0 += x1; x1 = rotl32(x1, 24); x1 ^= x0;
  x0 += ks2; x1 += k0 + 2u;
  x0 += x1; x1 = rotl32(x1, 13); x1 ^= x0;
  x0 += x1; x1 = rotl32(x1, 15); x1 ^= x0;
  x0 += x1; x1 = rotl32(x1, 26); x1 ^= x0;
  x0 += x1; x1 = rotl32(x1,  6); x1 ^= x0;
  x0 += k0; x1 += k1 + 3u;
  x0 += x1; x1 = rotl32(x1, 17); x1 ^= x0;
  x0 += x1; x1 = rotl32(x1, 29); x1 ^= x0;
  x0 += x1; x1 = rotl32(x1, 16); x1 ^= x0;
  x0 += x1; x1 = rotl32(x1, 24); x1 ^= x0;
  x0 += k1; x1 += ks2 + 4u;
  x0 += x1; x1 = rotl32(x1, 13); x1 ^= x0;
  x0 += x1; x1 = rotl32(x1, 15); x1 ^= x0;
  x0 += x1; x1 = rotl32(x1, 26); x1 ^= x0;
  x0 += x1; x1 = rotl32(x1,  6); x1 ^= x0;
  x0 += ks2; x1 += k0 + 5u;
  o0 = x0; o1 = x1;
}

// ---------- XLA-matched f32 special functions (no FMA contraction) ----------
__device__ __forceinline__ float tanh_xla(float x) {
  const float kMax = 7.90531110763549805f;
  float ax = fabsf(x);
  float xc = fminf(fmaxf(x, -kMax), kMax);
  float x2 = __fmul_rn(xc, xc);
  float p = -2.76076847742355e-16f;
  p = __fadd_rn(__fmul_rn(p, x2), 2.00018790482477e-13f);
  p = __fadd_rn(__fmul_rn(p, x2), -8.60467152213735e-10f);
  p = __fadd_rn(__fmul_rn(p, x2), 5.12229709037114e-08f);
  p = __fadd_rn(__fmul_rn(p, x2), 1.48572235717979e-05f);
  p = __fadd_rn(__fmul_rn(p, x2), 6.37261928875436e-04f);
  p = __fadd_rn(__fmul_rn(p, x2), 4.89352455891786e-03f);
  float num = __fmul_rn(xc, p);
  float q = 1.19825839466702e-06f;
  q = __fadd_rn(__fmul_rn(q, x2), 1.18534705686654e-04f);
  q = __fadd_rn(__fmul_rn(q, x2), 2.26843463243900e-03f);
  q = __fadd_rn(__fmul_rn(q, x2), 4.89352518554385e-03f);
  float r = __fdiv_rn(num, q);
  return (ax < 0.0004f) ? x : r;
}

__device__ __forceinline__ float sigmoid_xla(float x) {
  return __fadd_rn(0.5f, __fmul_rn(0.5f, tanh_xla(__fmul_rn(0.5f, x))));
}

__device__ __forceinline__ float log1p_xla(float x) {
  float u = __fadd_rn(x, 1.0f);
  if (u == 1.0f) return x;
  return __fmul_rn(logf(u), __fdiv_rn(x, __fsub_rn(u, 1.0f)));
}

__device__ __forceinline__ float erfinv_xla(float x) {
  float nx2 = -__fmul_rn(x, x);
  float w = -log1p_xla(nx2);
  float p;
  if (w < 5.0f) {
    w = __fsub_rn(w, 2.5f);
    p = 2.81022636e-08f;
    p = __fadd_rn(__fmul_rn(p, w), 3.43273939e-07f);
    p = __fadd_rn(__fmul_rn(p, w), -3.5233877e-06f);
    p = __fadd_rn(__fmul_rn(p, w), -4.39150654e-06f);
    p = __fadd_rn(__fmul_rn(p, w), 0.00021858087f);
    p = __fadd_rn(__fmul_rn(p, w), -0.00125372503f);
    p = __fadd_rn(__fmul_rn(p, w), -0.00417768164f);
    p = __fadd_rn(__fmul_rn(p, w), 0.246640727f);
    p = __fadd_rn(__fmul_rn(p, w), 1.50140941f);
  } else {
    w = __fsub_rn(__fsqrt_rn(w), 3.0f);
    p = -0.000200214257f;
    p = __fadd_rn(__fmul_rn(p, w), 0.000100950558f);
    p = __fadd_rn(__fmul_rn(p, w), 0.00134934322f);
    p = __fadd_rn(__fmul_rn(p, w), -0.00367342844f);
    p = __fadd_rn(__fmul_rn(p, w), 0.00573950773f);
    p = __fadd_rn(__fmul_rn(p, w), -0.0076224613f);
    p = __fadd_rn(__fmul_rn(p, w), 0.00943887047f);
    p = __fadd_rn(__fmul_rn(p, w), 1.00167406f);
    p = __fadd_rn(__fmul_rn(p, w), 2.83297682f);
  }
  return __fmul_rn(p, x);
}

__device__ __forceinline__ float bits_to_normal(uint32_t b) {
  uint32_t fb = (b >> 9) | 0x3f800000u;
  float f = __fsub_rn(__uint_as_float(fb), 1.0f);   // [0,1)
  const float lo = -0.99999994f;                    // nextafter(-1,0) in f32
  float u = __fadd_rn(__fmul_rn(f, 2.0f), lo);
  u = fmaxf(lo, u);
  return __fmul_rn(1.41421354f, erfinv_xla(u));
}

// ---------- fused single-kernel SocialLSTM ----------
struct SmA {                  // phase A: HW GEMM staging
  float hl[64][65];           // h half-tile (K split in two)
  float wl[128][64];          // Wa block (row-read only, no pad needed)
};
struct SmBC {                 // phase BC: gather + LSTM
  float A_[16][257];          // emb tile [e|a|h]
  float W_[32][129];          // weight chunk
  float posS[512];
  unsigned char cgS[16][256];
};

__global__ __launch_bounds__(256) void k_fused(
    const float* __restrict__ x_input, const float* __restrict__ We,
    const float* __restrict__ be, const float* __restrict__ Wa,
    const float* __restrict__ ba, const float* __restrict__ Wl,
    const float* __restrict__ Ul, const float* __restrict__ bl,
    const float* __restrict__ Wp, const float* __restrict__ bp,
    float* __restrict__ out, float* __restrict__ h0, float* __restrict__ h1,
    float* __restrict__ c, float* __restrict__ pos, float* __restrict__ HW) {
  cg::grid_group grid = cg::this_grid();
  __shared__ union { SmA a; SmBC b; } sm;
  const int blk = blockIdx.x;
  const int tid = threadIdx.x;

  // zero-init h0 and c (ws is poisoned 0xAA before every launch)
  {
    int idx = blk * 256 + tid;          // 256*256 = 65536 >= 32768: one pass
    if (idx < NPED * DH) { h0[idx] = 0.0f; c[idx] = 0.0f; }
  }
  fence_release_agent();
  grid.sync();
  fence_acquire_agent();

#pragma unroll 1
  for (int t = 0; t < TOBS + TPRED; ++t) {
    const float* hR = (t & 1) ? h1 : h0;   // h from previous step
    float* hW = (t & 1) ? h0 : h1;         // h written this step

    // ================= Phase A: HW GEMM (all 256 blocks); block 255 also does
    // pos/noise/o-projection afterwards.
    {
      const int g  = blk >> 2;
      const int jt = (blk & 3) * 64;
      for (int idx = tid; idx < DH * 64; idx += 256) {
        int r = idx >> 6, e2 = idx & 63;
        sm.a.wl[r][e2] = Wa[(g * DH + r) * 64 + e2];
      }
      const int jl = (tid >> 4) << 2;
      const int el = (tid & 15) << 2;
      float acc[4][4];
#pragma unroll
      for (int a = 0; a < 4; ++a)
#pragma unroll
        for (int b = 0; b < 4; ++b) acc[a][b] = 0.0f;
#pragma unroll 1
      for (int half = 0; half < 2; ++half) {
        __syncthreads();   // wl staged (half 0) / hl consumers done (half 1)
        for (int idx = tid; idx < 64 * 64; idx += 256) {
          int r = idx >> 6, d2 = idx & 63;
          sm.a.hl[r][d2] = hR[(jt + r) * DH + half * 64 + d2];
        }
        __syncthreads();
        for (int dl = 0; dl < 64; ++dl) {
          float av[4], bv[4];
#pragma unroll
          for (int a = 0; a < 4; ++a) av[a] = sm.a.hl[jl + a][dl];
#pragma unroll
          for (int b = 0; b < 4; ++b) bv[b] = sm.a.wl[half * 64 + dl][el + b];
#pragma unroll
          for (int a = 0; a < 4; ++a)
#pragma unroll
            for (int b = 0; b < 4; ++b) acc[a][b] = fmaf(av[a], bv[b], acc[a][b]);
        }
      }
#pragma unroll
      for (int a = 0; a < 4; ++a) {
        int j = jt + jl + a;
        float* dst = HW + (j * NG + g) * 64 + el;
#pragma unroll
        for (int b = 0; b < 4; ++b) dst[b] = acc[a][b];
      }
    }
    if (blk == NBLK - 1) {
      if (t < TOBS) {
        pos[tid * 2 + 0] = x_input[(t * NPED + tid) * 3 + 1];
        pos[tid * 2 + 1] = x_input[(t * NPED + tid) * 3 + 2];
      } else {
        uint32_t fk0, fk1;
        threefry2x32(0u, 42u, 0u, (uint32_t)(t - TOBS), fk0, fk1);
        uint32_t p0, p1, q0, q1;
        threefry2x32(fk0, fk1, 0u, (uint32_t)(2 * tid),     p0, p1);
        threefry2x32(fk0, fk1, 0u, (uint32_t)(2 * tid + 1), q0, q1);
        float z0 = bits_to_normal(p0 ^ p1);
        float z1 = bits_to_normal(q0 ^ q1);
        const int i = tid;
        float a0 = bp[0], a1 = bp[1], a2 = bp[2], a3 = bp[3], a4 = bp[4];
        for (int d = 0; d < DH; ++d) {
          float hv = hR[i * DH + d];
          a0 = fmaf(hv, Wp[d * 5 + 0], a0);
          a1 = fmaf(hv, Wp[d * 5 + 1], a1);
          a2 = fmaf(hv, Wp[d * 5 + 2], a2);
          a3 = fmaf(hv, Wp[d * 5 + 3], a3);
          a4 = fmaf(hv, Wp[d * 5 + 4], a4);
        }
        if (t >= TOBS + 1) {
          float* op = out + ((t - TOBS - 1) * NPED + i) * 5;
          op[0] = a0; op[1] = a1; op[2] = a2; op[3] = a3; op[4] = a4;
        }
        float sx = expf(a2), sy = expf(a3), r = tanh_xla(a4);
        float px = __fadd_rn(a0, __fmul_rn(sx, z0));
        float s1mr2 = __fsqrt_rn(__fsub_rn(1.0f, __fmul_rn(r, r)));
        float inner = __fadd_rn(__fmul_rn(r, z0), __fmul_rn(s1mr2, z1));
        float py = __fadd_rn(a1, __fmul_rn(sy, inner));
        pos[i * 2 + 0] = px;
        pos[i * 2 + 1] = py;
      }
    }
    fence_release_agent();
    grid.sync();
    fence_acquire_agent();

    // ================= Phase BC: gather + emb + LSTM (blocks 0..63)
    if (blk < 64) {
      const int i0 = (blk >> 2) << 4;      // 16-agent tile
      const int d0 = (blk & 3) << 5;       // 32-wide d slice (x4 gates)
      sm.b.posS[tid] = pos[tid];
      sm.b.posS[tid + 256] = pos[tid + 256];
      __syncthreads();
      // grid cells for this agent tile
      for (int r = 0; r < 16; ++r) {
        const int i = i0 + r;
        const float pix = sm.b.posS[2 * i], piy = sm.b.posS[2 * i + 1];
        const int j = tid;
        float rx = __fsub_rn(sm.b.posS[2 * j], pix);
        float ry = __fsub_rn(sm.b.posS[2 * j + 1], piy);
        float cx = floorf(__fmul_rn(__fadd_rn(rx, 2.0f), 2.0f));
        float cy = floorf(__fmul_rn(__fadd_rn(ry, 2.0f), 2.0f));
        unsigned char v = 255;
        if (cx >= 0.0f && cx < 8.0f && cy >= 0.0f && cy < 8.0f && j != i)
          v = (unsigned char)((int)cx * 8 + (int)cy);
        sm.b.cgS[r][j] = v;
      }
      // e-part and h-part of the emb tile
      {
        int idx = tid;
        for (int k = 0; k < 4; ++k, idx += 256) {
          int r = idx >> 6, e = idx & 63;
          float pix = sm.b.posS[2 * (i0 + r)], piy = sm.b.posS[2 * (i0 + r) + 1];
          float v = __fadd_rn(__fadd_rn(__fmul_rn(pix, We[e]),
                                        __fmul_rn(piy, We[NEMB + e])), be[e]);
          sm.b.A_[r][e] = fmaxf(v, 0.0f);
        }
        idx = tid;
        for (int k = 0; k < 8; ++k, idx += 256) {
          int r = idx >> 7, d = idx & 127;
          sm.b.A_[r][128 + d] = hR[(i0 + r) * DH + d];
        }
      }
      __syncthreads();
      // a-part: gather from HW, same quarter-sum association as verified R2
      {
        const int rg = tid >> 6, e = tid & 63;
        for (int round = 0; round < 4; ++round) {
          const int r = round * 4 + rg;
          float pacc[4];
#pragma unroll 1
          for (int q = 0; q < 4; ++q) {
            float a = 0.0f;
            for (int jj = 0; jj < 64; ++jj) {
              int j = (q << 6) + jj;
              int gidx = sm.b.cgS[r][j];
              if (gidx != 255) a = __fadd_rn(a, HW[(j * NG + gidx) * 64 + e]);
            }
            pacc[q] = a;
          }
          float s = __fadd_rn(__fadd_rn(__fadd_rn(pacc[0], pacc[1]),
                                        __fadd_rn(pacc[2], pacc[3])), ba[e]);
          sm.b.A_[r][NEMB + e] = fmaxf(s, 0.0f);
        }
      }
      // LSTM (identical structure/numerics to verified R2 k_lstm)
      const int dd = tid & 31;
      const int ip = tid >> 5;
      const int lc = tid & 127;
      const int col = ((lc >> 5) << 7) + d0 + (lc & 31);
      const int rbase = tid >> 7;
      float accW0[4] = {0,0,0,0}, accW1[4] = {0,0,0,0};
      float accU0[4] = {0,0,0,0}, accU1[4] = {0,0,0,0};
#pragma unroll 1
      for (int kc = 0; kc < 8; ++kc) {
        __syncthreads();
        for (int r2 = rbase; r2 < 32; r2 += 2) {
          int k = (kc << 5) + r2;
          sm.b.W_[r2][lc] = (k < 128) ? Wl[k * 512 + col] : Ul[(k - 128) * 512 + col];
        }
        __syncthreads();
        float* a0p = (kc < 4) ? accW0 : accU0;
        float* a1p = (kc < 4) ? accW1 : accU1;
#pragma unroll
        for (int kk = 0; kk < 32; ++kk) {
          float a0 = sm.b.A_[ip * 2 + 0][(kc << 5) + kk];
          float a1 = sm.b.A_[ip * 2 + 1][(kc << 5) + kk];
#pragma unroll
          for (int gt = 0; gt < 4; ++gt) {
            float wv = sm.b.W_[kk][(gt << 5) + dd];
            a0p[gt] = fmaf(a0, wv, a0p[gt]);
            a1p[gt] = fmaf(a1, wv, a1p[gt]);
          }
        }
      }
      const int d = d0 + dd;
#pragma unroll
      for (int p = 0; p < 2; ++p) {
        float* aW = p ? accW1 : accW0;
        float* aU = p ? accU1 : accU0;
        int i = i0 + ip * 2 + p;
        float zi = __fadd_rn(__fadd_rn(aW[0], aU[0]), bl[0 * DH + d]);
        float zf = __fadd_rn(__fadd_rn(aW[1], aU[1]), bl[1 * DH + d]);
        float zg = __fadd_rn(__fadd_rn(aW[2], aU[2]), bl[2 * DH + d]);
        float zo = __fadd_rn(__fadd_rn(aW[3], aU[3]), bl[3 * DH + d]);
        float cold = c[i * DH + d];
        float cn = __fadd_rn(__fmul_rn(sigmoid_xla(zf), cold),
                             __fmul_rn(sigmoid_xla(zi), tanh_xla(zg)));
        float hn = __fmul_rn(sigmoid_xla(zo), tanh_xla(cn));
        c[i * DH + d] = cn;
        hW[i * DH + d] = hn;
      }
    }
    fence_release_agent();
    grid.sync();
    fence_acquire_agent();
  }

  // final projection o(19) -> out row 11 (h after t=19 lives in h0)
  if (blk == NBLK - 1) {
    const int i = tid;
    float a0 = bp[0], a1 = bp[1], a2 = bp[2], a3 = bp[3], a4 = bp[4];
    for (int d = 0; d < DH; ++d) {
      float hv = h0[i * DH + d];
      a0 = fmaf(hv, Wp[d * 5 + 0], a0);
      a1 = fmaf(hv, Wp[d * 5 + 1], a1);
      a2 = fmaf(hv, Wp[d * 5 + 2], a2);
      a3 = fmaf(hv, Wp[d * 5 + 3], a3);
      a4 = fmaf(hv, Wp[d * 5 + 4], a4);
    }
    float* op = out + ((TPRED - 1) * NPED + i) * 5;
    op[0] = a0; op[1] = a1; op[2] = a2; op[3] = a3; op[4] = a4;
  }
}

extern "C" void kernel_launch(void* const* d_in, const int* in_sizes, int n_in,
                              void* d_out, int out_size, void* d_ws, size_t ws_size,
                              hipStream_t stream) {
  const float* x_input = (const float*)d_in[0];
  const float* We = (const float*)d_in[1];
  const float* be = (const float*)d_in[2];
  const float* Wa = (const float*)d_in[3];
  const float* ba = (const float*)d_in[4];
  const float* Wl = (const float*)d_in[5];
  const float* Ul = (const float*)d_in[6];
  const float* bl = (const float*)d_in[7];
  const float* Wp = (const float*)d_in[8];
  const float* bp = (const float*)d_in[9];
  float* out = (float*)d_out;
  float* ws = (float*)d_ws;

  float* h0  = ws;                 // 256*128
  float* h1  = ws + 32768;         // 256*128
  float* c   = ws + 65536;         // 256*128
  float* pos = ws + 98304;         // 512
  float* HW  = ws + 98816;         // 256*64*64 = 4 MB

  void* args[] = {(void*)&x_input, (void*)&We, (void*)&be, (void*)&Wa,
                  (void*)&ba, (void*)&Wl, (void*)&Ul, (void*)&bl,
                  (void*)&Wp, (void*)&bp, (void*)&out, (void*)&h0,
                  (void*)&h1, (void*)&c, (void*)&pos, (void*)&HW};
  hipLaunchCooperativeKernel((void*)k_fused, dim3(NBLK), dim3(256), args, 0,
                             stream);
}

// Round 8
// 1828.087 us; speedup vs baseline: 3.7791x; 3.7791x over previous
//
#include <hip/hip_runtime.h>
#include <stdint.h>

#define NPED 256   // agents
#define DH   128   // hidden dim
#define NEMB 64    // embedding dim
#define NG   64    // grid cells (8x8)
#define TOBS 8
#define TPRED 12
#define NBLK 256   // == CU count (1 block/CU at 49.4KB LDS)

#define SCOPE_AGENT __HIP_MEMORY_SCOPE_AGENT

// ---------- coherent (L2-bypassing, MALL-served) accessors for cross-block data
__device__ __forceinline__ float ld1(const float* p) {
  return __hip_atomic_load((float*)p, __ATOMIC_RELAXED, SCOPE_AGENT);
}
__device__ __forceinline__ void st1(float* p, float v) {
  __hip_atomic_store(p, v, __ATOMIC_RELAXED, SCOPE_AGENT);
}
__device__ __forceinline__ void ld2(const float* p, float& x, float& y) {
  unsigned long long r =
      __hip_atomic_load((unsigned long long*)p, __ATOMIC_RELAXED, SCOPE_AGENT);
  x = __uint_as_float((uint32_t)r);
  y = __uint_as_float((uint32_t)(r >> 32));
}
__device__ __forceinline__ void st2(float* p, float x, float y) {
  unsigned long long r = (unsigned long long)__float_as_uint(x) |
                         ((unsigned long long)__float_as_uint(y) << 32);
  __hip_atomic_store((unsigned long long*)p, r, __ATOMIC_RELAXED, SCOPE_AGENT);
}

// ---------- tree grid-barrier: NO cache maintenance (shared data is all sc1).
// bar[0..7]=leaf counters, bar[8]=root, bar[9]=epoch flag; all memset-0 on stream.
// Monotonic counters (no resets -> no reset/arrive race). __syncthreads() drains
// vmcnt so every thread's sc1 stores are at the coherence point before arrival.
// Spin is BOUNDED: on logic failure we finish with wrong data instead of
// hanging the GPU/container (diagnosable via absmax).
__device__ __forceinline__ void gbar(uint32_t* bar, int blk, int tid, uint32_t e) {
  __syncthreads();
  if (tid == 0) {
    uint32_t n = __hip_atomic_fetch_add(&bar[blk & 7], 1u, __ATOMIC_RELAXED, SCOPE_AGENT);
    if (n + 1u == 32u * e) {            // last of this leaf's 32 blocks, epoch e
      uint32_t m = __hip_atomic_fetch_add(&bar[8], 1u, __ATOMIC_RELAXED, SCOPE_AGENT);
      if (m + 1u == 8u * e)             // last leaf
        __hip_atomic_store(&bar[9], e, __ATOMIC_RELAXED, SCOPE_AGENT);
    }
    for (int spin = 0; spin < 4000000; ++spin) {
      if (__hip_atomic_load(&bar[9], __ATOMIC_RELAXED, SCOPE_AGENT) >= e) break;
      __builtin_amdgcn_s_sleep(2);
    }
  }
  __syncthreads();
}

// ---------- JAX-compatible Threefry2x32 ----------
__device__ __forceinline__ uint32_t rotl32(uint32_t v, int n) {
  return (v << n) | (v >> (32 - n));
}

__device__ __forceinline__ void threefry2x32(uint32_t k0, uint32_t k1,
                                             uint32_t x0, uint32_t x1,
                                             uint32_t& o0, uint32_t& o1) {
  uint32_t ks2 = k0 ^ k1 ^ 0x1BD11BDAu;
  x0 += k0; x1 += k1;
  x0 += x1; x1 = rotl32(x1, 13); x1 ^= x0;
  x0 += x1; x1 = rotl32(x1, 15); x1 ^= x0;
  x0 += x1; x1 = rotl32(x1, 26); x1 ^= x0;
  x0 += x1; x1 = rotl32(x1,  6); x1 ^= x0;
  x0 += k1; x1 += ks2 + 1u;
  x0 += x1; x1 = rotl32(x1, 17); x1 ^= x0;
  x0 += x1; x1 = rotl32(x1, 29); x1 ^= x0;
  x0 += x1; x1 = rotl32(x1, 16); x1 ^= x0;
  x0 += x1; x1 = rotl32(x1, 24); x1 ^= x0;
  x0 += ks2; x1 += k0 + 2u;
  x0 += x1; x1 = rotl32(x1, 13); x1 ^= x0;
  x0 += x1; x1 = rotl32(x1, 15); x1 ^= x0;
  x0 += x1; x1 = rotl32(x1, 26); x1 ^= x0;
  x0 += x1; x1 = rotl32(x1,  6); x1 ^= x0;
  x0 += k0; x1 += k1 + 3u;
  x0 += x1; x1 = rotl32(x1, 17); x1 ^= x0;
  x0 += x1; x1 = rotl32(x1, 29); x1 ^= x0;
  x0 += x1; x1 = rotl32(x1, 16); x1 ^= x0;
  x0 += x1; x1 = rotl32(x1, 24); x1 ^= x0;
  x0 += k1; x1 += ks2 + 4u;
  x0 += x1; x1 = rotl32(x1, 13); x1 ^= x0;
  x0 += x1; x1 = rotl32(x1, 15); x1 ^= x0;
  x0 += x1; x1 = rotl32(x1, 26); x1 ^= x0;
  x0 += x1; x1 = rotl32(x1,  6); x1 ^= x0;
  x0 += ks2; x1 += k0 + 5u;
  o0 = x0; o1 = x1;
}

// ---------- XLA-matched f32 special functions (no FMA contraction) ----------
__device__ __forceinline__ float tanh_xla(float x) {
  const float kMax = 7.90531110763549805f;
  float ax = fabsf(x);
  float xc = fminf(fmaxf(x, -kMax), kMax);
  float x2 = __fmul_rn(xc, xc);
  float p = -2.76076847742355e-16f;
  p = __fadd_rn(__fmul_rn(p, x2), 2.00018790482477e-13f);
  p = __fadd_rn(__fmul_rn(p, x2), -8.60467152213735e-10f);
  p = __fadd_rn(__fmul_rn(p, x2), 5.12229709037114e-08f);
  p = __fadd_rn(__fmul_rn(p, x2), 1.48572235717979e-05f);
  p = __fadd_rn(__fmul_rn(p, x2), 6.37261928875436e-04f);
  p = __fadd_rn(__fmul_rn(p, x2), 4.89352455891786e-03f);
  float num = __fmul_rn(xc, p);
  float q = 1.19825839466702e-06f;
  q = __fadd_rn(__fmul_rn(q, x2), 1.18534705686654e-04f);
  q = __fadd_rn(__fmul_rn(q, x2), 2.26843463243900e-03f);
  q = __fadd_rn(__fmul_rn(q, x2), 4.89352518554385e-03f);
  float r = __fdiv_rn(num, q);
  return (ax < 0.0004f) ? x : r;
}

__device__ __forceinline__ float sigmoid_xla(float x) {
  return __fadd_rn(0.5f, __fmul_rn(0.5f, tanh_xla(__fmul_rn(0.5f, x))));
}

__device__ __forceinline__ float log1p_xla(float x) {
  float u = __fadd_rn(x, 1.0f);
  if (u == 1.0f) return x;
  return __fmul_rn(logf(u), __fdiv_rn(x, __fsub_rn(u, 1.0f)));
}

__device__ __forceinline__ float erfinv_xla(float x) {
  float nx2 = -__fmul_rn(x, x);
  float w = -log1p_xla(nx2);
  float p;
  if (w < 5.0f) {
    w = __fsub_rn(w, 2.5f);
    p = 2.81022636e-08f;
    p = __fadd_rn(__fmul_rn(p, w), 3.43273939e-07f);
    p = __fadd_rn(__fmul_rn(p, w), -3.5233877e-06f);
    p = __fadd_rn(__fmul_rn(p, w), -4.39150654e-06f);
    p = __fadd_rn(__fmul_rn(p, w), 0.00021858087f);
    p = __fadd_rn(__fmul_rn(p, w), -0.00125372503f);
    p = __fadd_rn(__fmul_rn(p, w), -0.00417768164f);
    p = __fadd_rn(__fmul_rn(p, w), 0.246640727f);
    p = __fadd_rn(__fmul_rn(p, w), 1.50140941f);
  } else {
    w = __fsub_rn(__fsqrt_rn(w), 3.0f);
    p = -0.000200214257f;
    p = __fadd_rn(__fmul_rn(p, w), 0.000100950558f);
    p = __fadd_rn(__fmul_rn(p, w), 0.00134934322f);
    p = __fadd_rn(__fmul_rn(p, w), -0.00367342844f);
    p = __fadd_rn(__fmul_rn(p, w), 0.00573950773f);
    p = __fadd_rn(__fmul_rn(p, w), -0.0076224613f);
    p = __fadd_rn(__fmul_rn(p, w), 0.00943887047f);
    p = __fadd_rn(__fmul_rn(p, w), 1.00167406f);
    p = __fadd_rn(__fmul_rn(p, w), 2.83297682f);
  }
  return __fmul_rn(p, x);
}

__device__ __forceinline__ float bits_to_normal(uint32_t b) {
  uint32_t fb = (b >> 9) | 0x3f800000u;
  float f = __fsub_rn(__uint_as_float(fb), 1.0f);   // [0,1)
  const float lo = -0.99999994f;                    // nextafter(-1,0) in f32
  float u = __fadd_rn(__fmul_rn(f, 2.0f), lo);
  u = fmaxf(lo, u);
  return __fmul_rn(1.41421354f, erfinv_xla(u));
}

// ---------- LDS unions ----------
struct SmA {                  // phase A: HW GEMM staging (~49.4 KB)
  float hl[64][65];           // h half-tile (K split in two); row 0 reused for o-proj
  float wl[128][64];
};
struct SmB {                  // phase B: gather
  float posS[512];
  float red[4][NEMB];
  unsigned char cgS[NPED];
};
struct SmC {                  // phase C: emb + LSTM (~35 KB)
  float A_[16][257];
  float W_[32][129];
  float posS[512];
};

__global__ __launch_bounds__(256) void k_fused(
    const float* __restrict__ x_input, const float* __restrict__ We,
    const float* __restrict__ be, const float* __restrict__ Wa,
    const float* __restrict__ ba, const float* __restrict__ Wl,
    const float* __restrict__ Ul, const float* __restrict__ bl,
    const float* __restrict__ Wp, const float* __restrict__ bp,
    float* __restrict__ out, float* __restrict__ h0, float* __restrict__ h1,
    float* __restrict__ c, float* __restrict__ pos, float* __restrict__ a_buf,
    float* __restrict__ HW, uint32_t* __restrict__ bar) {
  const int blk = blockIdx.x;
  const int tid = threadIdx.x;
  __shared__ union { SmA a; SmB b; SmC c2; } sm;
  uint32_t ep = 0;

#pragma unroll 1
  for (int t = 0; t < TOBS + TPRED; ++t) {
    const float* hR = (t & 1) ? h1 : h0;   // h from previous step
    float* hW = (t & 1) ? h0 : h1;         // h written this step

    // ========== Phase A: HW GEMM (all blocks) + per-block agent o/noise/pos ==========
    {
      const int g  = blk >> 2;
      const int jt = (blk & 3) * 64;
      for (int idx = tid; idx < DH * 64; idx += 256) {
        int r = idx >> 6, e2 = idx & 63;
        sm.a.wl[r][e2] = Wa[(g * DH + r) * 64 + e2];   // read-only: normal, L2-hot
      }
      const int jl = (tid >> 4) << 2;
      const int el = (tid & 15) << 2;
      float acc[4][4];
#pragma unroll
      for (int a2 = 0; a2 < 4; ++a2)
#pragma unroll
        for (int b2 = 0; b2 < 4; ++b2) acc[a2][b2] = 0.0f;
#pragma unroll 1
      for (int half = 0; half < 2; ++half) {
        __syncthreads();
        for (int k2 = tid; k2 < 2048; k2 += 256) {      // 64x64 floats as u64 pairs
          int r = k2 >> 5, cc = (k2 & 31) << 1;
          float x, y;
          ld2(&hR[(jt + r) * DH + half * 64 + cc], x, y);
          sm.a.hl[r][cc] = x; sm.a.hl[r][cc + 1] = y;
        }
        __syncthreads();
        for (int dl = 0; dl < 64; ++dl) {
          float av[4], bv[4];
#pragma unroll
          for (int a2 = 0; a2 < 4; ++a2) av[a2] = sm.a.hl[jl + a2][dl];
#pragma unroll
          for (int b2 = 0; b2 < 4; ++b2) bv[b2] = sm.a.wl[half * 64 + dl][el + b2];
#pragma unroll
          for (int a2 = 0; a2 < 4; ++a2)
#pragma unroll
            for (int b2 = 0; b2 < 4; ++b2)
              acc[a2][b2] = fmaf(av[a2], bv[b2], acc[a2][b2]);
        }
      }
#pragma unroll
      for (int a2 = 0; a2 < 4; ++a2) {
        int j = jt + jl + a2;
        float* dst = HW + (j * NG + g) * 64 + el;
        st2(dst, acc[a2][0], acc[a2][1]);
        st2(dst + 2, acc[a2][2], acc[a2][3]);
      }
      // stage this block's agent h-row (for o-projection), reuse hl row 0
      __syncthreads();
      for (int k = tid; k < DH; k += 256) sm.a.hl[0][k] = ld1(&hR[blk * DH + k]);
      __syncthreads();
      if (tid == 0) {
        const int i = blk;
        if (t < TOBS) {
          float px = x_input[(t * NPED + i) * 3 + 1];
          float py = x_input[(t * NPED + i) * 3 + 2];
          st2(&pos[i * 2], px, py);
        } else {
          uint32_t fk0, fk1;
          threefry2x32(0u, 42u, 0u, (uint32_t)(t - TOBS), fk0, fk1);
          uint32_t p0, p1, q0, q1;
          threefry2x32(fk0, fk1, 0u, (uint32_t)(2 * i),     p0, p1);
          threefry2x32(fk0, fk1, 0u, (uint32_t)(2 * i + 1), q0, q1);
          float z0 = bits_to_normal(p0 ^ p1);
          float z1 = bits_to_normal(q0 ^ q1);
          float a0 = bp[0], a1 = bp[1], a2 = bp[2], a3 = bp[3], a4 = bp[4];
          for (int d = 0; d < DH; ++d) {
            float hv = sm.a.hl[0][d];
            a0 = fmaf(hv, Wp[d * 5 + 0], a0);
            a1 = fmaf(hv, Wp[d * 5 + 1], a1);
            a2 = fmaf(hv, Wp[d * 5 + 2], a2);
            a3 = fmaf(hv, Wp[d * 5 + 3], a3);
            a4 = fmaf(hv, Wp[d * 5 + 4], a4);
          }
          if (t >= TOBS + 1) {
            float* op = out + ((t - TOBS - 1) * NPED + i) * 5;
            op[0] = a0; op[1] = a1; op[2] = a2; op[3] = a3; op[4] = a4;
          }
          float sx = expf(a2), sy = expf(a3), r = tanh_xla(a4);
          float px = __fadd_rn(a0, __fmul_rn(sx, z0));
          float s1mr2 = __fsqrt_rn(__fsub_rn(1.0f, __fmul_rn(r, r)));
          float inner = __fadd_rn(__fmul_rn(r, z0), __fmul_rn(s1mr2, z1));
          float py = __fadd_rn(a1, __fmul_rn(sy, inner));
          st2(&pos[i * 2], px, py);
        }
      }
    }
    gbar(bar, blk, tid, ++ep);

    // ========== Phase B: social gather, one agent per block ==========
    {
      const int i = blk;
      { float x, y; ld2(&pos[tid * 2], x, y);
        sm.b.posS[tid * 2] = x; sm.b.posS[tid * 2 + 1] = y; }
      __syncthreads();
      const float pix = sm.b.posS[2 * i], piy = sm.b.posS[2 * i + 1];
      {
        const int j = tid;
        float rx = __fsub_rn(sm.b.posS[2 * j], pix);
        float ry = __fsub_rn(sm.b.posS[2 * j + 1], piy);
        float cx = floorf(__fmul_rn(__fadd_rn(rx, 2.0f), 2.0f));
        float cy = floorf(__fmul_rn(__fadd_rn(ry, 2.0f), 2.0f));
        unsigned char v = 255;
        if (cx >= 0.0f && cx < 8.0f && cy >= 0.0f && cy < 8.0f && j != i)
          v = (unsigned char)((int)cx * 8 + (int)cy);
        sm.b.cgS[j] = v;
      }
      __syncthreads();
      if (tid < 128) {                       // 4 quarters x 32 e-pairs
        const int q = tid >> 5;
        const int e2 = (tid & 31) << 1;
        float s0 = 0.0f, s1 = 0.0f;
#pragma unroll 4
        for (int jj = 0; jj < 64; ++jj) {
          int j = (q << 6) + jj;
          int gidx = sm.b.cgS[j];
          if (gidx != 255) {
            float x, y; ld2(&HW[(j * NG + gidx) * 64 + e2], x, y);
            s0 = __fadd_rn(s0, x);           // same per-e chain order as R2
            s1 = __fadd_rn(s1, y);
          }
        }
        sm.b.red[q][e2] = s0; sm.b.red[q][e2 + 1] = s1;
      }
      __syncthreads();
      if (tid < 64) {
        int e = tid;
        float s = __fadd_rn(__fadd_rn(__fadd_rn(sm.b.red[0][e], sm.b.red[1][e]),
                                      __fadd_rn(sm.b.red[2][e], sm.b.red[3][e])),
                            ba[e]);
        st1(&a_buf[i * 64 + e], fmaxf(s, 0.0f));
      }
    }
    gbar(bar, blk, tid, ++ep);

    // ========== Phase C: emb assembly + LSTM (blocks 0..63) ==========
    if (blk < 64) {
      const int i0 = (blk >> 2) << 4;
      const int d0 = (blk & 3) << 5;
      { float x, y; ld2(&pos[tid * 2], x, y);
        sm.c2.posS[tid * 2] = x; sm.c2.posS[tid * 2 + 1] = y; }
      __syncthreads();
      for (int r = 0; r < 16; ++r) {
        const int i = i0 + r;
        float v;
        if (tid < 64) {
          float pix = sm.c2.posS[2 * i], piy = sm.c2.posS[2 * i + 1];
          v = fmaxf(__fadd_rn(__fadd_rn(__fmul_rn(pix, We[tid]),
                                        __fmul_rn(piy, We[NEMB + tid])), be[tid]),
                    0.0f);
        } else if (tid < 128) {
          v = ld1(&a_buf[i * 64 + (tid - 64)]);
        } else {
          v = ld1(&hR[i * DH + (tid - 128)]);
        }
        sm.c2.A_[r][tid] = v;
      }
      const int dd = tid & 31;
      const int ip = tid >> 5;
      const int lc = tid & 127;
      const int col = ((lc >> 5) << 7) + d0 + (lc & 31);
      const int rbase = tid >> 7;
      float accW0[4] = {0,0,0,0}, accW1[4] = {0,0,0,0};
      float accU0[4] = {0,0,0,0}, accU1[4] = {0,0,0,0};
#pragma unroll 1
      for (int kc = 0; kc < 8; ++kc) {
        __syncthreads();
        for (int r2 = rbase; r2 < 32; r2 += 2) {
          int k = (kc << 5) + r2;
          sm.c2.W_[r2][lc] = (k < 128) ? Wl[k * 512 + col]
                                       : Ul[(k - 128) * 512 + col];  // L2-hot
        }
        __syncthreads();
        float* a0p = (kc < 4) ? accW0 : accU0;
        float* a1p = (kc < 4) ? accW1 : accU1;
#pragma unroll
        for (int kk = 0; kk < 32; ++kk) {
          float a0 = sm.c2.A_[ip * 2 + 0][(kc << 5) + kk];
          float a1 = sm.c2.A_[ip * 2 + 1][(kc << 5) + kk];
#pragma unroll
          for (int gt = 0; gt < 4; ++gt) {
            float wv = sm.c2.W_[kk][(gt << 5) + dd];
            a0p[gt] = fmaf(a0, wv, a0p[gt]);
            a1p[gt] = fmaf(a1, wv, a1p[gt]);
          }
        }
      }
      const int d = d0 + dd;
#pragma unroll
      for (int p = 0; p < 2; ++p) {
        float* aW = p ? accW1 : accW0;
        float* aU = p ? accU1 : accU0;
        int i = i0 + ip * 2 + p;
        float zi = __fadd_rn(__fadd_rn(aW[0], aU[0]), bl[0 * DH + d]);
        float zf = __fadd_rn(__fadd_rn(aW[1], aU[1]), bl[1 * DH + d]);
        float zg = __fadd_rn(__fadd_rn(aW[2], aU[2]), bl[2 * DH + d]);
        float zo = __fadd_rn(__fadd_rn(aW[3], aU[3]), bl[3 * DH + d]);
        float cold = c[i * DH + d];          // block-private: normal mem
        float cn = __fadd_rn(__fmul_rn(sigmoid_xla(zf), cold),
                             __fmul_rn(sigmoid_xla(zi), tanh_xla(zg)));
        float hn = __fmul_rn(sigmoid_xla(zo), tanh_xla(cn));
        c[i * DH + d] = cn;
        st1(&hW[i * DH + d], hn);            // cross-block: coherent store
      }
    }
    gbar(bar, blk, tid, ++ep);
  }

  // ========== final o(19) -> out row 11, agent = blk ==========
  {
    for (int k = tid; k < DH; k += 256) sm.a.hl[0][k] = ld1(&h0[blk * DH + k]);
    __syncthreads();
    if (tid == 0) {
      const int i = blk;
      float a0 = bp[0], a1 = bp[1], a2 = bp[2], a3 = bp[3], a4 = bp[4];
      for (int d = 0; d < DH; ++d) {
        float hv = sm.a.hl[0][d];
        a0 = fmaf(hv, Wp[d * 5 + 0], a0);
        a1 = fmaf(hv, Wp[d * 5 + 1], a1);
        a2 = fmaf(hv, Wp[d * 5 + 2], a2);
        a3 = fmaf(hv, Wp[d * 5 + 3], a3);
        a4 = fmaf(hv, Wp[d * 5 + 4], a4);
      }
      float* op = out + ((TPRED - 1) * NPED + i) * 5;
      op[0] = a0; op[1] = a1; op[2] = a2; op[3] = a3; op[4] = a4;
    }
  }
}

extern "C" void kernel_launch(void* const* d_in, const int* in_sizes, int n_in,
                              void* d_out, int out_size, void* d_ws, size_t ws_size,
                              hipStream_t stream) {
  const float* x_input = (const float*)d_in[0];
  const float* We = (const float*)d_in[1];
  const float* be = (const float*)d_in[2];
  const float* Wa = (const float*)d_in[3];
  const float* ba = (const float*)d_in[4];
  const float* Wl = (const float*)d_in[5];
  const float* Ul = (const float*)d_in[6];
  const float* bl = (const float*)d_in[7];
  const float* Wp = (const float*)d_in[8];
  const float* bp = (const float*)d_in[9];
  float* out = (float*)d_out;
  float* ws = (float*)d_ws;

  // layout: [h0 32768 | c 32768 | bar 64 | h1 32768 | pos 512 | a 16384 | HW 1M]
  float*    h0    = ws;
  float*    c     = ws + 32768;
  uint32_t* bar   = (uint32_t*)(ws + 65536);
  float*    h1    = ws + 65536 + 64;
  float*    pos   = h1 + 32768;
  float*    a_buf = pos + 512;
  float*    HW    = a_buf + 16384;

  // zero h0, c, and barrier state in one stream memset (graph-capture safe);
  // kernel-dispatch boundary makes these zeros coherent for all XCDs.
  hipMemsetAsync(ws, 0, (size_t)(65536 + 64) * sizeof(float), stream);

  void* args[] = {(void*)&x_input, (void*)&We, (void*)&be, (void*)&Wa,
                  (void*)&ba, (void*)&Wl, (void*)&Ul, (void*)&bl,
                  (void*)&Wp, (void*)&bp, (void*)&out, (void*)&h0,
                  (void*)&h1, (void*)&c, (void*)&pos, (void*)&a_buf,
                  (void*)&HW, (void*)&bar};
  hipLaunchCooperativeKernel((void*)k_fused, dim3(NBLK), dim3(256), args, 0,
                             stream);
}

// Round 12
// 1423.475 us; speedup vs baseline: 4.8533x; 1.2842x over previous
//
#include <hip/hip_runtime.h>
#include <stdint.h>

#define NPED 256   // agents
#define DH   128   // hidden dim
#define NEMB 64    // embedding dim
#define NG   64    // grid cells (8x8)
#define TOBS 8
#define TPRED 12
#define NBLK 256   // == CU count (1 block/CU at 49.4KB LDS)

#define SCOPE_AGENT __HIP_MEMORY_SCOPE_AGENT

// ---------- coherent (L2-bypassing, MALL-served) accessors for cross-block data
__device__ __forceinline__ float ld1(const float* p) {
  return __hip_atomic_load((float*)p, __ATOMIC_RELAXED, SCOPE_AGENT);
}
__device__ __forceinline__ void st1(float* p, float v) {
  __hip_atomic_store(p, v, __ATOMIC_RELAXED, SCOPE_AGENT);
}
__device__ __forceinline__ void ld2(const float* p, float& x, float& y) {
  unsigned long long r =
      __hip_atomic_load((unsigned long long*)p, __ATOMIC_RELAXED, SCOPE_AGENT);
  x = __uint_as_float((uint32_t)r);
  y = __uint_as_float((uint32_t)(r >> 32));
}
__device__ __forceinline__ void st2(float* p, float x, float y) {
  unsigned long long r = (unsigned long long)__float_as_uint(x) |
                         ((unsigned long long)__float_as_uint(y) << 32);
  __hip_atomic_store((unsigned long long*)p, r, __ATOMIC_RELAXED, SCOPE_AGENT);
}
__device__ __forceinline__ uint32_t ldu(const uint32_t* p) {
  return __hip_atomic_load((uint32_t*)p, __ATOMIC_RELAXED, SCOPE_AGENT);
}
__device__ __forceinline__ void stu(uint32_t* p, uint32_t v) {
  __hip_atomic_store(p, v, __ATOMIC_RELAXED, SCOPE_AGENT);
}

// ---------- flag-based grid barrier: ZERO contended RMWs.
// flags[blk] = per-block arrival epoch (own slot, parallel stores).
// flags[256..259] -> rel word at flags[256]. Block 0's 256 threads each watch
// one arrival flag in parallel, then tid0 publishes rel=e. Others spin on rel.
// __syncthreads() before arrival drains vmcnt -> all sc1 data stores are at the
// coherence point before the flag store issues. Spins BOUNDED (hang-guard).
__device__ __forceinline__ void gbar(uint32_t* flags, int blk, int tid, uint32_t e) {
  __syncthreads();
  if (blk == 0) {
    if (tid >= 1) {                       // watch flags[1..255]
      for (int spin = 0; spin < 2000000; ++spin) {
        if (ldu(&flags[tid]) >= e) break;
        __builtin_amdgcn_s_sleep(1);
      }
    }
    __syncthreads();
    if (tid == 0) stu(&flags[256], e);    // release
  } else {
    if (tid == 0) {
      stu(&flags[blk], e);                // arrival (own slot, no contention)
      for (int spin = 0; spin < 2000000; ++spin) {
        if (ldu(&flags[256]) >= e) break;
        __builtin_amdgcn_s_sleep(1);
      }
    }
    __syncthreads();
  }
}

// ---------- JAX-compatible Threefry2x32 ----------
__device__ __forceinline__ uint32_t rotl32(uint32_t v, int n) {
  return (v << n) | (v >> (32 - n));
}

__device__ __forceinline__ void threefry2x32(uint32_t k0, uint32_t k1,
                                             uint32_t x0, uint32_t x1,
                                             uint32_t& o0, uint32_t& o1) {
  uint32_t ks2 = k0 ^ k1 ^ 0x1BD11BDAu;
  x0 += k0; x1 += k1;
  x0 += x1; x1 = rotl32(x1, 13); x1 ^= x0;
  x0 += x1; x1 = rotl32(x1, 15); x1 ^= x0;
  x0 += x1; x1 = rotl32(x1, 26); x1 ^= x0;
  x0 += x1; x1 = rotl32(x1,  6); x1 ^= x0;
  x0 += k1; x1 += ks2 + 1u;
  x0 += x1; x1 = rotl32(x1, 17); x1 ^= x0;
  x0 += x1; x1 = rotl32(x1, 29); x1 ^= x0;
  x0 += x1; x1 = rotl32(x1, 16); x1 ^= x0;
  x0 += x1; x1 = rotl32(x1, 24); x1 ^= x0;
  x0 += ks2; x1 += k0 + 2u;
  x0 += x1; x1 = rotl32(x1, 13); x1 ^= x0;
  x0 += x1; x1 = rotl32(x1, 15); x1 ^= x0;
  x0 += x1; x1 = rotl32(x1, 26); x1 ^= x0;
  x0 += x1; x1 = rotl32(x1,  6); x1 ^= x0;
  x0 += k0; x1 += k1 + 3u;
  x0 += x1; x1 = rotl32(x1, 17); x1 ^= x0;
  x0 += x1; x1 = rotl32(x1, 29); x1 ^= x0;
  x0 += x1; x1 = rotl32(x1, 16); x1 ^= x0;
  x0 += x1; x1 = rotl32(x1, 24); x1 ^= x0;
  x0 += k1; x1 += ks2 + 4u;
  x0 += x1; x1 = rotl32(x1, 13); x1 ^= x0;
  x0 += x1; x1 = rotl32(x1, 15); x1 ^= x0;
  x0 += x1; x1 = rotl32(x1, 26); x1 ^= x0;
  x0 += x1; x1 = rotl32(x1,  6); x1 ^= x0;
  x0 += ks2; x1 += k0 + 5u;
  o0 = x0; o1 = x1;
}

// ---------- XLA-matched f32 special functions (no FMA contraction) ----------
__device__ __forceinline__ float tanh_xla(float x) {
  const float kMax = 7.90531110763549805f;
  float ax = fabsf(x);
  float xc = fminf(fmaxf(x, -kMax), kMax);
  float x2 = __fmul_rn(xc, xc);
  float p = -2.76076847742355e-16f;
  p = __fadd_rn(__fmul_rn(p, x2), 2.00018790482477e-13f);
  p = __fadd_rn(__fmul_rn(p, x2), -8.60467152213735e-10f);
  p = __fadd_rn(__fmul_rn(p, x2), 5.12229709037114e-08f);
  p = __fadd_rn(__fmul_rn(p, x2), 1.48572235717979e-05f);
  p = __fadd_rn(__fmul_rn(p, x2), 6.37261928875436e-04f);
  p = __fadd_rn(__fmul_rn(p, x2), 4.89352455891786e-03f);
  float num = __fmul_rn(xc, p);
  float q = 1.19825839466702e-06f;
  q = __fadd_rn(__fmul_rn(q, x2), 1.18534705686654e-04f);
  q = __fadd_rn(__fmul_rn(q, x2), 2.26843463243900e-03f);
  q = __fadd_rn(__fmul_rn(q, x2), 4.89352518554385e-03f);
  float r = __fdiv_rn(num, q);
  return (ax < 0.0004f) ? x : r;
}

__device__ __forceinline__ float sigmoid_xla(float x) {
  return __fadd_rn(0.5f, __fmul_rn(0.5f, tanh_xla(__fmul_rn(0.5f, x))));
}

__device__ __forceinline__ float log1p_xla(float x) {
  float u = __fadd_rn(x, 1.0f);
  if (u == 1.0f) return x;
  return __fmul_rn(logf(u), __fdiv_rn(x, __fsub_rn(u, 1.0f)));
}

__device__ __forceinline__ float erfinv_xla(float x) {
  float nx2 = -__fmul_rn(x, x);
  float w = -log1p_xla(nx2);
  float p;
  if (w < 5.0f) {
    w = __fsub_rn(w, 2.5f);
    p = 2.81022636e-08f;
    p = __fadd_rn(__fmul_rn(p, w), 3.43273939e-07f);
    p = __fadd_rn(__fmul_rn(p, w), -3.5233877e-06f);
    p = __fadd_rn(__fmul_rn(p, w), -4.39150654e-06f);
    p = __fadd_rn(__fmul_rn(p, w), 0.00021858087f);
    p = __fadd_rn(__fmul_rn(p, w), -0.00125372503f);
    p = __fadd_rn(__fmul_rn(p, w), -0.00417768164f);
    p = __fadd_rn(__fmul_rn(p, w), 0.246640727f);
    p = __fadd_rn(__fmul_rn(p, w), 1.50140941f);
  } else {
    w = __fsub_rn(__fsqrt_rn(w), 3.0f);
    p = -0.000200214257f;
    p = __fadd_rn(__fmul_rn(p, w), 0.000100950558f);
    p = __fadd_rn(__fmul_rn(p, w), 0.00134934322f);
    p = __fadd_rn(__fmul_rn(p, w), -0.00367342844f);
    p = __fadd_rn(__fmul_rn(p, w), 0.00573950773f);
    p = __fadd_rn(__fmul_rn(p, w), -0.0076224613f);
    p = __fadd_rn(__fmul_rn(p, w), 0.00943887047f);
    p = __fadd_rn(__fmul_rn(p, w), 1.00167406f);
    p = __fadd_rn(__fmul_rn(p, w), 2.83297682f);
  }
  return __fmul_rn(p, x);
}

__device__ __forceinline__ float bits_to_normal(uint32_t b) {
  uint32_t fb = (b >> 9) | 0x3f800000u;
  float f = __fsub_rn(__uint_as_float(fb), 1.0f);   // [0,1)
  const float lo = -0.99999994f;                    // nextafter(-1,0) in f32
  float u = __fadd_rn(__fmul_rn(f, 2.0f), lo);
  u = fmaxf(lo, u);
  return __fmul_rn(1.41421354f, erfinv_xla(u));
}

// ---------- LDS unions ----------
struct SmA {                  // phase A: HW GEMM staging (~49.4 KB)
  float hl[64][65];           // h half-tile (K split in two); row 0 reused for o-proj
  float wl[128][64];
};
struct SmB {                  // phase B: gather
  float posS[512];
  float red[4][NEMB];
  unsigned char cgS[NPED];
};
struct SmC {                  // phase C: emb + LSTM (~35 KB)
  float A_[16][257];
  float W_[32][129];
  float posS[512];
};

__global__ __launch_bounds__(256) void k_fused(
    const float* __restrict__ x_input, const float* __restrict__ We,
    const float* __restrict__ be, const float* __restrict__ Wa,
    const float* __restrict__ ba, const float* __restrict__ Wl,
    const float* __restrict__ Ul, const float* __restrict__ bl,
    const float* __restrict__ Wp, const float* __restrict__ bp,
    float* __restrict__ out, float* __restrict__ h0, float* __restrict__ h1,
    float* __restrict__ c, float* __restrict__ pos, float* __restrict__ a_buf,
    float* __restrict__ HW, uint32_t* __restrict__ flags) {
  const int blk = blockIdx.x;
  const int tid = threadIdx.x;
  __shared__ union { SmA a; SmB b; SmC c2; } sm;
  uint32_t ep = 0;

#pragma unroll 1
  for (int t = 0; t < TOBS + TPRED; ++t) {
    const float* hR = (t & 1) ? h1 : h0;   // h from previous step
    float* hW = (t & 1) ? h0 : h1;         // h written this step

    // ========== Phase A: HW GEMM (all blocks) + per-block agent o/noise/pos ==========
    {
      const int g  = blk >> 2;
      const int jt = (blk & 3) * 64;
      for (int idx = tid; idx < DH * 64; idx += 256) {
        int r = idx >> 6, e2 = idx & 63;
        sm.a.wl[r][e2] = Wa[(g * DH + r) * 64 + e2];   // read-only: normal, L2-hot
      }
      const int jl = (tid >> 4) << 2;
      const int el = (tid & 15) << 2;
      float acc[4][4];
#pragma unroll
      for (int a2 = 0; a2 < 4; ++a2)
#pragma unroll
        for (int b2 = 0; b2 < 4; ++b2) acc[a2][b2] = 0.0f;
#pragma unroll 1
      for (int half = 0; half < 2; ++half) {
        __syncthreads();
        for (int k2 = tid; k2 < 2048; k2 += 256) {      // 64x64 floats as u64 pairs
          int r = k2 >> 5, cc = (k2 & 31) << 1;
          float x, y;
          ld2(&hR[(jt + r) * DH + half * 64 + cc], x, y);
          sm.a.hl[r][cc] = x; sm.a.hl[r][cc + 1] = y;
        }
        __syncthreads();
        for (int dl = 0; dl < 64; ++dl) {
          float av[4], bv[4];
#pragma unroll
          for (int a2 = 0; a2 < 4; ++a2) av[a2] = sm.a.hl[jl + a2][dl];
#pragma unroll
          for (int b2 = 0; b2 < 4; ++b2) bv[b2] = sm.a.wl[half * 64 + dl][el + b2];
#pragma unroll
          for (int a2 = 0; a2 < 4; ++a2)
#pragma unroll
            for (int b2 = 0; b2 < 4; ++b2)
              acc[a2][b2] = fmaf(av[a2], bv[b2], acc[a2][b2]);
        }
      }
#pragma unroll
      for (int a2 = 0; a2 < 4; ++a2) {
        int j = jt + jl + a2;
        float* dst = HW + (j * NG + g) * 64 + el;
        st2(dst, acc[a2][0], acc[a2][1]);
        st2(dst + 2, acc[a2][2], acc[a2][3]);
      }
      // stage this block's agent h-row (for o-projection), reuse hl row 0
      __syncthreads();
      for (int k = tid; k < DH; k += 256) sm.a.hl[0][k] = ld1(&hR[blk * DH + k]);
      __syncthreads();
      if (tid == 0) {
        const int i = blk;
        if (t < TOBS) {
          float px = x_input[(t * NPED + i) * 3 + 1];
          float py = x_input[(t * NPED + i) * 3 + 2];
          st2(&pos[i * 2], px, py);
        } else {
          uint32_t fk0, fk1;
          threefry2x32(0u, 42u, 0u, (uint32_t)(t - TOBS), fk0, fk1);
          uint32_t p0, p1, q0, q1;
          threefry2x32(fk0, fk1, 0u, (uint32_t)(2 * i),     p0, p1);
          threefry2x32(fk0, fk1, 0u, (uint32_t)(2 * i + 1), q0, q1);
          float z0 = bits_to_normal(p0 ^ p1);
          float z1 = bits_to_normal(q0 ^ q1);
          float a0 = bp[0], a1 = bp[1], a2 = bp[2], a3 = bp[3], a4 = bp[4];
          for (int d = 0; d < DH; ++d) {
            float hv = sm.a.hl[0][d];
            a0 = fmaf(hv, Wp[d * 5 + 0], a0);
            a1 = fmaf(hv, Wp[d * 5 + 1], a1);
            a2 = fmaf(hv, Wp[d * 5 + 2], a2);
            a3 = fmaf(hv, Wp[d * 5 + 3], a3);
            a4 = fmaf(hv, Wp[d * 5 + 4], a4);
          }
          if (t >= TOBS + 1) {
            float* op = out + ((t - TOBS - 1) * NPED + i) * 5;
            op[0] = a0; op[1] = a1; op[2] = a2; op[3] = a3; op[4] = a4;
          }
          float sx = expf(a2), sy = expf(a3), r = tanh_xla(a4);
          float px = __fadd_rn(a0, __fmul_rn(sx, z0));
          float s1mr2 = __fsqrt_rn(__fsub_rn(1.0f, __fmul_rn(r, r)));
          float inner = __fadd_rn(__fmul_rn(r, z0), __fmul_rn(s1mr2, z1));
          float py = __fadd_rn(a1, __fmul_rn(sy, inner));
          st2(&pos[i * 2], px, py);
        }
      }
    }
    gbar(flags, blk, tid, ++ep);

    // ========== Phase B: social gather, one agent per block (R2-exact form) ====
    {
      const int i = blk;
      { float x, y; ld2(&pos[tid * 2], x, y);
        sm.b.posS[tid * 2] = x; sm.b.posS[tid * 2 + 1] = y; }
      __syncthreads();
      const float pix = sm.b.posS[2 * i], piy = sm.b.posS[2 * i + 1];
      {
        const int j = tid;
        float rx = __fsub_rn(sm.b.posS[2 * j], pix);
        float ry = __fsub_rn(sm.b.posS[2 * j + 1], piy);
        float cx = floorf(__fmul_rn(__fadd_rn(rx, 2.0f), 2.0f));
        float cy = floorf(__fmul_rn(__fadd_rn(ry, 2.0f), 2.0f));
        unsigned char v = 255;
        if (cx >= 0.0f && cx < 8.0f && cy >= 0.0f && cy < 8.0f && j != i)
          v = (unsigned char)((int)cx * 8 + (int)cy);
        sm.b.cgS[j] = v;
      }
      __syncthreads();
      {
        const int q = tid >> 6;            // 4 quarters, wave-uniform j
        const int e = tid & 63;
        float acc = 0.0f;
#pragma unroll 8
        for (int jj = 0; jj < 64; ++jj) {
          int j = (q << 6) + jj;
          int gidx = sm.b.cgS[j];
          if (gidx != 255)
            acc = __fadd_rn(acc, ld1(&HW[(j * NG + gidx) * 64 + e]));
        }
        sm.b.red[q][e] = acc;
      }
      __syncthreads();
      if (tid < 64) {
        int e = tid;
        float s = __fadd_rn(__fadd_rn(__fadd_rn(sm.b.red[0][e], sm.b.red[1][e]),
                                      __fadd_rn(sm.b.red[2][e], sm.b.red[3][e])),
                            ba[e]);
        st1(&a_buf[i * 64 + e], fmaxf(s, 0.0f));
      }
    }
    gbar(flags, blk, tid, ++ep);

    // ========== Phase C: emb assembly + LSTM (blocks 0..63) ==========
    if (blk < 64) {
      const int i0 = (blk >> 2) << 4;
      const int d0 = (blk & 3) << 5;
      { float x, y; ld2(&pos[tid * 2], x, y);
        sm.c2.posS[tid * 2] = x; sm.c2.posS[tid * 2 + 1] = y; }
      __syncthreads();
      for (int r = 0; r < 16; ++r) {
        const int i = i0 + r;
        float v;
        if (tid < 64) {
          float pix = sm.c2.posS[2 * i], piy = sm.c2.posS[2 * i + 1];
          v = fmaxf(__fadd_rn(__fadd_rn(__fmul_rn(pix, We[tid]),
                                        __fmul_rn(piy, We[NEMB + tid])), be[tid]),
                    0.0f);
        } else if (tid < 128) {
          v = ld1(&a_buf[i * 64 + (tid - 64)]);
        } else {
          v = ld1(&hR[i * DH + (tid - 128)]);
        }
        sm.c2.A_[r][tid] = v;
      }
      const int dd = tid & 31;
      const int ip = tid >> 5;
      const int lc = tid & 127;
      const int col = ((lc >> 5) << 7) + d0 + (lc & 31);
      const int rbase = tid >> 7;
      float accW0[4] = {0,0,0,0}, accW1[4] = {0,0,0,0};
      float accU0[4] = {0,0,0,0}, accU1[4] = {0,0,0,0};
#pragma unroll 1
      for (int kc = 0; kc < 8; ++kc) {
        __syncthreads();
        for (int r2 = rbase; r2 < 32; r2 += 2) {
          int k = (kc << 5) + r2;
          sm.c2.W_[r2][lc] = (k < 128) ? Wl[k * 512 + col]
                                       : Ul[(k - 128) * 512 + col];  // L2-hot
        }
        __syncthreads();
        float* a0p = (kc < 4) ? accW0 : accU0;
        float* a1p = (kc < 4) ? accW1 : accU1;
#pragma unroll
        for (int kk = 0; kk < 32; ++kk) {
          float a0 = sm.c2.A_[ip * 2 + 0][(kc << 5) + kk];
          float a1 = sm.c2.A_[ip * 2 + 1][(kc << 5) + kk];
#pragma unroll
          for (int gt = 0; gt < 4; ++gt) {
            float wv = sm.c2.W_[kk][(gt << 5) + dd];
            a0p[gt] = fmaf(a0, wv, a0p[gt]);
            a1p[gt] = fmaf(a1, wv, a1p[gt]);
          }
        }
      }
      const int d = d0 + dd;
#pragma unroll
      for (int p = 0; p < 2; ++p) {
        float* aW = p ? accW1 : accW0;
        float* aU = p ? accU1 : accU0;
        int i = i0 + ip * 2 + p;
        float zi = __fadd_rn(__fadd_rn(aW[0], aU[0]), bl[0 * DH + d]);
        float zf = __fadd_rn(__fadd_rn(aW[1], aU[1]), bl[1 * DH + d]);
        float zg = __fadd_rn(__fadd_rn(aW[2], aU[2]), bl[2 * DH + d]);
        float zo = __fadd_rn(__fadd_rn(aW[3], aU[3]), bl[3 * DH + d]);
        float cold = c[i * DH + d];          // block-private: normal mem
        float cn = __fadd_rn(__fmul_rn(sigmoid_xla(zf), cold),
                             __fmul_rn(sigmoid_xla(zi), tanh_xla(zg)));
        float hn = __fmul_rn(sigmoid_xla(zo), tanh_xla(cn));
        c[i * DH + d] = cn;
        st1(&hW[i * DH + d], hn);            // cross-block: coherent store
      }
    }
    gbar(flags, blk, tid, ++ep);
  }

  // ========== final o(19) -> out row 11, agent = blk ==========
  {
    for (int k = tid; k < DH; k += 256) sm.a.hl[0][k] = ld1(&h0[blk * DH + k]);
    __syncthreads();
    if (tid == 0) {
      const int i = blk;
      float a0 = bp[0], a1 = bp[1], a2 = bp[2], a3 = bp[3], a4 = bp[4];
      for (int d = 0; d < DH; ++d) {
        float hv = sm.a.hl[0][d];
        a0 = fmaf(hv, Wp[d * 5 + 0], a0);
        a1 = fmaf(hv, Wp[d * 5 + 1], a1);
        a2 = fmaf(hv, Wp[d * 5 + 2], a2);
        a3 = fmaf(hv, Wp[d * 5 + 3], a3);
        a4 = fmaf(hv, Wp[d * 5 + 4], a4);
      }
      float* op = out + ((TPRED - 1) * NPED + i) * 5;
      op[0] = a0; op[1] = a1; op[2] = a2; op[3] = a3; op[4] = a4;
    }
  }
}

extern "C" void kernel_launch(void* const* d_in, const int* in_sizes, int n_in,
                              void* d_out, int out_size, void* d_ws, size_t ws_size,
                              hipStream_t stream) {
  const float* x_input = (const float*)d_in[0];
  const float* We = (const float*)d_in[1];
  const float* be = (const float*)d_in[2];
  const float* Wa = (const float*)d_in[3];
  const float* ba = (const float*)d_in[4];
  const float* Wl = (const float*)d_in[5];
  const float* Ul = (const float*)d_in[6];
  const float* bl = (const float*)d_in[7];
  const float* Wp = (const float*)d_in[8];
  const float* bp = (const float*)d_in[9];
  float* out = (float*)d_out;
  float* ws = (float*)d_ws;

  // layout: [h0 32768 | c 32768 | flags 512u32 | h1 32768 | pos 512 | a 16384 | HW 1M]
  float*    h0    = ws;
  float*    c     = ws + 32768;
  uint32_t* flags = (uint32_t*)(ws + 65536);
  float*    h1    = ws + 65536 + 512;
  float*    pos   = h1 + 32768;
  float*    a_buf = pos + 512;
  float*    HW    = a_buf + 16384;

  // zero h0, c, and barrier flags in one stream memset (graph-capture safe);
  // kernel-dispatch boundary makes these zeros coherent for all XCDs.
  hipMemsetAsync(ws, 0, (size_t)(65536 + 512) * sizeof(float), stream);

  void* args[] = {(void*)&x_input, (void*)&We, (void*)&be, (void*)&Wa,
                  (void*)&ba, (void*)&Wl, (void*)&Ul, (void*)&bl,
                  (void*)&Wp, (void*)&bp, (void*)&out, (void*)&h0,
                  (void*)&h1, (void*)&c, (void*)&pos, (void*)&a_buf,
                  (void*)&HW, (void*)&flags};
  hipLaunchCooperativeKernel((void*)k_fused, dim3(NBLK), dim3(256), args, 0,
                             stream);
}